// Round 6
// baseline (373.588 us; speedup 1.0000x reference)
//
#include <hip/hip_runtime.h>
#include <hip/hip_bf16.h>
#include <cstdint>
#include <cstddef>

typedef __bf16 bf16;
typedef bf16 bf16x8 __attribute__((ext_vector_type(8)));
typedef bf16 bf16x4 __attribute__((ext_vector_type(4)));
typedef float f32x4 __attribute__((ext_vector_type(4)));
typedef unsigned int u32;

#define DEV static __device__ __forceinline__

DEV f32x4 mfma16(bf16x8 a, bf16x8 b, f32x4 c) {
    return __builtin_amdgcn_mfma_f32_16x16x32_bf16(a, b, c, 0, 0, 0);
}

DEV f32x4 shflx4(f32x4 v, int m) {
    f32x4 r;
    for (int i = 0; i < 4; ++i) r[i] = __shfl_xor(v[i], m, 64);
    return r;
}

DEV bf16x8 cvt8(const float* p) {
    float4 f0 = *(const float4*)p;
    float4 f1 = *(const float4*)(p + 4);
    bf16x8 v;
    v[0] = (bf16)f0.x; v[1] = (bf16)f0.y; v[2] = (bf16)f0.z; v[3] = (bf16)f0.w;
    v[4] = (bf16)f1.x; v[5] = (bf16)f1.y; v[6] = (bf16)f1.z; v[7] = (bf16)f1.w;
    return v;
}

// async global->LDS, 16B/lane; global addr per-lane, LDS base wave-uniform.
DEV void glo(const bf16* g, bf16* l) {
    __builtin_amdgcn_global_load_lds(
        (const __attribute__((address_space(1))) u32*)g,
        (__attribute__((address_space(3))) u32*)l,
        16, 0, 0);
}

// fused "wait outstanding vmem <= n, then barrier" — counted, never reorder.
#define WAITB(n) asm volatile("s_waitcnt vmcnt(" #n ")\n\ts_barrier" ::: "memory")
#define BAR()    asm volatile("s_barrier" ::: "memory")

// ---------------------------------------------------------------------------
// Prep (weights + mask only; activation cvt is FUSED into proj_gemm r6):
//   z<6 : weight transpose+cvt W[K][N]fp32 -> Wt[N][K]bf16 (stride-param
//         so Wv/Wtv interleave into WT5[1024][2048])
//   z 6..9 : maskprep for b = z-6 (blockIdx.y<8 active)
// grid (16, 16, 10), 256 threads.
// ---------------------------------------------------------------------------
struct PrepArgs {
    const float* w[6];
    const float* mask;
    bf16* wdst[6];  int wstride[6];
    bf16* maskR;
};

__global__ __launch_bounds__(256) void prep_kernel(PrepArgs p)
{
    const int z = blockIdx.z;
    const int t = threadIdx.x;
    if (z < 6) {
        __shared__ bf16 tile[64][72];
        const float* src = p.w[z];
        bf16* out = p.wdst[z];
        const int os = p.wstride[z];
        const int r = t >> 3, c8 = (t & 7) * 8;
        const int row0 = blockIdx.y * 64, col0 = blockIdx.x * 64;
        *(bf16x8*)&tile[r][c8]      = cvt8(&src[(size_t)(row0 + r) * 1024 + col0 + c8]);
        *(bf16x8*)&tile[r + 32][c8] = cvt8(&src[(size_t)(row0 + r + 32) * 1024 + col0 + c8]);
        __syncthreads();
        for (int half = 0; half < 2; ++half) {
            int rr = r + half * 32;
            bf16x8 v;
            for (int j = 0; j < 8; ++j) v[j] = tile[c8 + j][rr];
            *(bf16x8*)&out[(size_t)(col0 + rr) * os + row0 + c8] = v;
        }
    } else {
        // maskprep: mask[b][i][j] fp32 -> maskR[(b,it,jt)][tid][e] bf16
        if (blockIdx.y >= 8) return;
        const int jt = blockIdx.x, it = blockIdx.y, b = z - 6;
        __shared__ bf16 Mt[128 * 72];
        const int lane = t & 63, w = t >> 6;
        const int ln = lane & 15, qd = lane >> 4;
        {
            const int il = t >> 1, jh = (t & 1) * 32;
            const float* src = &p.mask[((size_t)b * 1024 + it * 128 + il) * 1024 + jt * 64 + jh];
            *(bf16x8*)&Mt[il * 72 + jh]      = cvt8(src);
            *(bf16x8*)&Mt[il * 72 + jh + 8]  = cvt8(src + 8);
            *(bf16x8*)&Mt[il * 72 + jh + 16] = cvt8(src + 16);
            *(bf16x8*)&Mt[il * 72 + jh + 24] = cvt8(src + 24);
        }
        __syncthreads();
        bf16 m[32];
        for (int si = 0; si < 2; ++si)
            for (int jc = 0; jc < 4; ++jc)
                for (int r = 0; r < 4; ++r) {
                    const int il = w * 32 + si * 16 + qd * 4 + r;
                    const int jl = jc * 16 + ln;
                    m[(si * 4 + jc) * 4 + r] = Mt[il * 72 + jl];
                }
        bf16* dst = &p.maskR[((((size_t)b * 8 + it) * 16 + jt) * 256 + t) * 32];
        for (int c = 0; c < 4; ++c)
            *(bf16x8*)&dst[c * 8] = *(const bf16x8*)&m[c * 8];
    }
}

// ---------------------------------------------------------------------------
// Projection GEMMs, 4 z-slices. A-side reads the ORIGINAL fp32 activations
// directly (reg-staged: 32B fp32/lane at the swizzled column -> cvt8 ->
// ds_write_b128 into the SAME LDS layout the glo path used; read side
// unchanged). Saves prep's 80MB act read + 40MB write + proj's 40MB re-read.
// W-side stays glo (bf16 weights). A-loads for tile k+1 issue right after
// the 2nd barrier -> latency hides under compute(k). K=2048 slice (z3 =
// [value|time_v] @ [Wv;Wtv]) selects source on wave-uniform bk<1024.
// 128x128 tile, 4 waves x 64x64, BK=64, XOR swizzle (0 conflicts measured).
// __launch_bounds__(256,4) pins VGPR<=128 (occupancy cliff guard).
// Grid (32 my, 8 nx, 4): linear%8 = my%8 -> same-A blocks share an XCD.
// ---------------------------------------------------------------------------
struct ProjArgs {
    const float* A0[4];
    const float* A1[4];     // source for k>=1024 (z3 only)
    const bf16* W[4];
    const float* bias[4];
    const float* bias2[4];
    bf16* out[4];
    int vst[4];
    int nk[4];
};

__global__ __launch_bounds__(256, 4) void proj_gemm(ProjArgs pa)
{
    const int z = blockIdx.z;
    const float* __restrict__ A0 = pa.A0[z];
    const float* __restrict__ A1 = pa.A1[z];
    const bf16* __restrict__ W = pa.W[z];
    const int nk = pa.nk[z];
    const int lda = nk << 6;
    const int m0 = blockIdx.x * 128, n0 = blockIdx.y * 128;
    __shared__ bf16 As[128 * 64];
    __shared__ bf16 Bs[128 * 64];
    const int t = threadIdx.x, lane = t & 63, w = t >> 6;
    const int ln = lane & 15, qd = lane >> 4;
    const int wm0 = (w >> 1) * 64, wn0 = (w & 1) * 64;
    const int sub0 = w * 4;
    const int rr = lane >> 3;
    const int cbs = (((lane & 7) ^ rr)) * 8;   // swizzled source column
    const int lx = ln & 7;                     // row&7 for fragment rows
    f32x4 acc[4][4];
    for (int i = 0; i < 4; ++i)
        for (int j = 0; j < 4; ++j)
            acc[i][j] = (f32x4){0.f, 0.f, 0.f, 0.f};

    bf16x8 av[4];
    auto loadA = [&](int ks) {
        const int bk = ks * 64;
        const float* src = (bk < 1024) ? A0 : A1;   // wave-uniform
        const int acol = (bk & 1023) + cbs;
        for (int i = 0; i < 4; ++i) {
            const int row = (sub0 + i) * 8 + rr;
            av[i] = cvt8(&src[(size_t)(m0 + row) * 1024 + acol]);
        }
    };

    loadA(0);
    for (int ks = 0; ks < nk; ++ks) {
        const int bk = ks * 64;
        __syncthreads();
        for (int i = 0; i < 4; ++i) {
            const int row = (sub0 + i) * 8 + rr;
            glo(&W[(size_t)(n0 + row) * lda + bk + cbs], &Bs[(sub0 + i) * 512]);
        }
        for (int i = 0; i < 4; ++i)
            *(bf16x8*)&As[(sub0 + i) * 512 + lane * 8] = av[i];
        __syncthreads();
        if (ks + 1 < nk) loadA(ks + 1);        // latency under compute(ks)
        for (int kc = 0; kc < 2; ++kc) {
            const int sg = ((kc * 4 + qd) ^ lx) * 8;
            bf16x8 af[4], bfr[4];
            for (int mi = 0; mi < 4; ++mi)
                af[mi] = *(const bf16x8*)&As[(wm0 + mi * 16 + ln) * 64 + sg];
            for (int ni = 0; ni < 4; ++ni)
                bfr[ni] = *(const bf16x8*)&Bs[(wn0 + ni * 16 + ln) * 64 + sg];
            for (int mi = 0; mi < 4; ++mi)
                for (int ni = 0; ni < 4; ++ni)
                    acc[mi][ni] = mfma16(af[mi], bfr[ni], acc[mi][ni]);
        }
    }
    const float* bias = pa.bias[z];
    const float* bias2 = pa.bias2[z];
    bf16* out = pa.out[z];
    const int vst = pa.vst[z];
    for (int ni = 0; ni < 4; ++ni) {
        const int n = n0 + wn0 + ni * 16 + ln;
        const float bv = bias[n] + (bias2 ? bias2[n] : 0.0f);
        for (int mi = 0; mi < 4; ++mi) {
            const int mbase = m0 + wm0 + mi * 16 + qd * 4;
            f32x4 v = acc[mi][ni];
            if (vst) {
                const int b = mbase >> 10, s = mbase & 1023;
                bf16x4 pk;
                for (int r = 0; r < 4; ++r) pk[r] = (bf16)(v[r] + bv);
                *(bf16x4*)&out[((size_t)(b * 1024 + n)) * 1024 + s] = pk;
            } else {
                for (int r = 0; r < 4; ++r)
                    out[(size_t)(mbase + r) * 1024 + n] = (bf16)(v[r] + bv);
            }
        }
    }
}

// ---------------------------------------------------------------------------
// Attention: i-tile 128, j-tile 64, grid (16h,8it,4b)=512 = 2 blocks/CU
// (grid-capped, so the double buffer is occupancy-FREE: 66.5KB < 80KB).
// Per jt: BAR (all waves past reads of buf^1) -> stage jt+1 into buf^1
// (6 glo/wave) -> vmcnt(6)+BAR (buf jt resident; jt+1 in flight under
// compute) -> QK/softmax/PV on buf jt. vmcnt never drains to 0 until jt=15.
// K/QJ/V staged via glo+XOR-swizzle; V from fused Vsum GEMM ([d][s] bf16).
// mask from maskR registers (issued before BAR, covered by vmcnt(6)).
// ---------------------------------------------------------------------------
__global__ __launch_bounds__(256) void attn6_kernel(
    const bf16* __restrict__ Qb, const bf16* __restrict__ Kb, const bf16* __restrict__ TKb,
    const bf16* __restrict__ Vsum,
    const bf16* __restrict__ maskR, bf16* __restrict__ ctx)
{
    const int h = blockIdx.x, it = blockIdx.y, b = blockIdx.z;
    const int i0 = it * 128;
    __shared__ bf16 Ks[2][64 * 64];
    __shared__ bf16 QJs[2][64 * 64];
    __shared__ bf16 Vs[2][64 * 64];
    __shared__ bf16 Ps[128][68];
    const int t = threadIdx.x, lane = t & 63, w = t >> 6;
    const int ln = lane & 15, qd = lane >> 4;
    const int lx = ln & 7;
    const int rr = lane >> 3;
    const int cbs = ((lane & 7) ^ rr) * 8;
    const size_t baseQ = ((size_t)b * 1024) * 1024 + (size_t)h * 64;
    const size_t baseV = ((size_t)b * 1024 + h * 64) * 1024;

    bf16x8 qf[2][2], tkf[2][2];
    for (int si = 0; si < 2; ++si) {
        const size_t row = (size_t)(i0 + w * 32 + si * 16 + ln);
        for (int kc = 0; kc < 2; ++kc) {
            qf[si][kc]  = *(const bf16x8*)&Qb [baseQ + row * 1024 + kc * 32 + qd * 8];
            tkf[si][kc] = *(const bf16x8*)&TKb[baseQ + row * 1024 + kc * 32 + qd * 8];
        }
    }

    f32x4 O[2][4];
    f32x4 psum[2];
    for (int si = 0; si < 2; ++si) {
        psum[si] = (f32x4){0.f, 0.f, 0.f, 0.f};
        for (int dc = 0; dc < 4; ++dc) O[si][dc] = (f32x4){0.f, 0.f, 0.f, 0.f};
    }

    const float c1 = 0.045084439f;   // log2(e)/32
    const float c2 = 1.442695041f;   // log2(e)

    const size_t mtile0 = (((size_t)b * 8 + it) * 16) * 256 + t;

    // stage j-tile jt into buffer jt&1: 24 units (6 glo per wave)
    auto stage = [&](int jt) {
        const int buf = jt & 1;
        const int j0 = jt * 64;
        for (int i = 0; i < 6; ++i) {
            const int u = w * 6 + i;
            if (u < 8) {
                glo(&Kb[baseQ + (size_t)(j0 + u * 8 + rr) * 1024 + cbs], &Ks[buf][u * 512]);
            } else if (u < 16) {
                const int s = u - 8;
                glo(&Qb[baseQ + (size_t)(j0 + s * 8 + rr) * 1024 + cbs], &QJs[buf][s * 512]);
            } else {
                const int s = u - 16;
                glo(&Vsum[baseV + (size_t)(s * 8 + rr) * 1024 + j0 + cbs], &Vs[buf][s * 512]);
            }
        }
    };

    stage(0);

    for (int jt = 0; jt < 16; ++jt) {
        const int cur = jt & 1;
        bf16x8 mm[4];
        {
            const bf16* mb = &maskR[(mtile0 + (size_t)jt * 256) * 32];
            for (int c = 0; c < 4; ++c) mm[c] = *(const bf16x8*)&mb[c * 8];
        }
        BAR();                       // all waves done reading buf[cur^1]
        if (jt < 15) {
            stage(jt + 1);           // into buf[cur^1]; stays in flight
            WAITB(6);                // buf[cur] + mm resident; 6 outstanding
        } else {
            WAITB(0);
        }

        f32x4 sc[2][4];
        for (int jc = 0; jc < 4; ++jc) {
            bf16x8 kf[2], qjf[2];
            for (int kc = 0; kc < 2; ++kc) {
                const int sg = ((kc * 4 + qd) ^ lx) * 8;
                kf[kc]  = *(const bf16x8*)&Ks [cur][(jc * 16 + ln) * 64 + sg];
                qjf[kc] = *(const bf16x8*)&QJs[cur][(jc * 16 + ln) * 64 + sg];
            }
            for (int si = 0; si < 2; ++si) {
                f32x4 a = (f32x4){0.f, 0.f, 0.f, 0.f};
                a = mfma16(qf[si][0], kf[0], a);
                a = mfma16(qf[si][1], kf[1], a);
                a = mfma16(tkf[si][0], qjf[0], a);
                a = mfma16(tkf[si][1], qjf[1], a);
                sc[si][jc] = a;
            }
        }
        for (int si = 0; si < 2; ++si) {
            const int ibl = w * 32 + si * 16 + qd * 4;
            for (int jc = 0; jc < 4; ++jc) {
                const int jl = jc * 16 + ln;
                const int e = si * 4 + jc;
                for (int r = 0; r < 4; ++r) {
                    const float mval = (float)mm[e >> 1][(e & 1) * 4 + r];
                    const float p = exp2f(fmaf(sc[si][jc][r], c1, mval * c2));
                    psum[si][r] += p;
                    Ps[ibl + r][jl] = (bf16)p;
                }
            }
        }
        for (int kc = 0; kc < 2; ++kc) {
            bf16x8 pa[2], vb[4];
            for (int si = 0; si < 2; ++si) {
                bf16x4 lo = *(const bf16x4*)&Ps[w * 32 + si * 16 + ln][kc * 32 + qd * 8];
                bf16x4 hi = *(const bf16x4*)&Ps[w * 32 + si * 16 + ln][kc * 32 + qd * 8 + 4];
                for (int e = 0; e < 4; ++e) { pa[si][e] = lo[e]; pa[si][4 + e] = hi[e]; }
            }
            for (int dc = 0; dc < 4; ++dc) {
                const int vrow = dc * 16 + ln;
                const int sg = ((kc * 4 + qd) ^ lx) * 8;
                vb[dc] = *(const bf16x8*)&Vs[cur][vrow * 64 + sg];
            }
            for (int si = 0; si < 2; ++si)
                for (int dc = 0; dc < 4; ++dc)
                    O[si][dc] = mfma16(pa[si], vb[dc], O[si][dc]);
        }
    }

    for (int si = 0; si < 2; ++si) {
        for (int m = 1; m <= 8; m <<= 1) psum[si] += shflx4(psum[si], m);
        f32x4 rl;
        for (int r = 0; r < 4; ++r) rl[r] = 1.0f / psum[si][r];
        const int ibase = i0 + w * 32 + si * 16 + qd * 4;
        for (int dc = 0; dc < 4; ++dc) {
            const int d = h * 64 + dc * 16 + ln;
            f32x4 v = O[si][dc] * rl;
            for (int r = 0; r < 4; ++r)
                ctx[((size_t)b * 1024 + ibase + r) * 1024 + d] = (bf16)v[r];
        }
    }
}

// ---------------------------------------------------------------------------
// Final GEMM: out[m][n] = ctx[m][k]*WmT[n][k] + bm, fp32 out.
// 64m x 128n tile, grid (64 my, 8 nx) = 512 = 2 blocks/CU (grid-capped ->
// double buffer free: 48KB). Same counted-vmcnt pattern as attn6.
// ---------------------------------------------------------------------------
__global__ __launch_bounds__(256) void out_gemm(
    const bf16* __restrict__ A, const bf16* __restrict__ W,
    const float* __restrict__ bias, float* __restrict__ out)
{
    const int m0 = blockIdx.x * 64, n0 = blockIdx.y * 128;
    __shared__ bf16 As[2][64 * 64];
    __shared__ bf16 Bs[2][128 * 64];
    const int t = threadIdx.x, lane = t & 63, w = t >> 6;
    const int ln = lane & 15, qd = lane >> 4;
    const int wn0 = w * 32;
    const int rr = lane >> 3;
    const int cbs = ((lane & 7) ^ rr) * 8;
    const int lx = ln & 7;
    f32x4 acc[4][2];
    for (int i = 0; i < 4; ++i)
        for (int j = 0; j < 2; ++j)
            acc[i][j] = (f32x4){0.f, 0.f, 0.f, 0.f};

    auto stage = [&](int ks) {
        const int buf = ks & 1;
        const int bk = ks * 64;
        for (int i = 0; i < 6; ++i) {
            const int u = w * 6 + i;
            if (u < 8) {
                glo(&A[(size_t)(m0 + u * 8 + rr) * 1024 + bk + cbs], &As[buf][u * 512]);
            } else {
                const int sub = u - 8;
                glo(&W[(size_t)(n0 + sub * 8 + rr) * 1024 + bk + cbs], &Bs[buf][sub * 512]);
            }
        }
    };

    stage(0);

    for (int ks = 0; ks < 16; ++ks) {
        const int cur = ks & 1;
        BAR();                       // all waves done reading buf[cur^1]
        if (ks < 15) {
            stage(ks + 1);
            WAITB(6);
        } else {
            WAITB(0);
        }
        for (int kc = 0; kc < 2; ++kc) {
            const int sg = ((kc * 4 + qd) ^ lx) * 8;
            bf16x8 af[4], bfr[2];
            for (int mi = 0; mi < 4; ++mi)
                af[mi] = *(const bf16x8*)&As[cur][(mi * 16 + ln) * 64 + sg];
            for (int ni = 0; ni < 2; ++ni)
                bfr[ni] = *(const bf16x8*)&Bs[cur][(wn0 + ni * 16 + ln) * 64 + sg];
            for (int mi = 0; mi < 4; ++mi)
                for (int ni = 0; ni < 2; ++ni)
                    acc[mi][ni] = mfma16(af[mi], bfr[ni], acc[mi][ni]);
        }
    }
    for (int ni = 0; ni < 2; ++ni) {
        const int n = n0 + wn0 + ni * 16 + ln;
        const float bv = bias[n];
        for (int mi = 0; mi < 4; ++mi) {
            const int mbase = m0 + mi * 16 + qd * 4;
            f32x4 v = acc[mi][ni];
            for (int r = 0; r < 4; ++r)
                out[(size_t)(mbase + r) * 1024 + n] = v[r] + bv;
        }
    }
}

// ---------------------------------------------------------------------------
extern "C" void kernel_launch(void* const* d_in, const int* in_sizes, int n_in,
                              void* d_out, int out_size, void* d_ws, size_t ws_size,
                              hipStream_t stream)
{
    (void)in_sizes; (void)n_in; (void)out_size; (void)ws_size;
    const float* query  = (const float*)d_in[0];
    const float* key    = (const float*)d_in[1];
    const float* value  = (const float*)d_in[2];
    const float* time_k = (const float*)d_in[3];
    const float* time_v = (const float*)d_in[4];
    const float* mask   = (const float*)d_in[5];
    const float* Wq  = (const float*)d_in[6];  const float* bq  = (const float*)d_in[7];
    const float* Wk  = (const float*)d_in[8];  const float* bk  = (const float*)d_in[9];
    const float* Wv  = (const float*)d_in[10]; const float* bv  = (const float*)d_in[11];
    const float* Wtk = (const float*)d_in[12]; const float* btk = (const float*)d_in[13];
    const float* Wtv = (const float*)d_in[14]; const float* btv = (const float*)d_in[15];
    const float* Wm  = (const float*)d_in[16]; const float* bm  = (const float*)d_in[17];

    bf16* ws = (bf16*)d_ws;
    const size_t MM = (size_t)1024 * 1024;
    bf16* WTq  = ws + 0 * MM;        // [1024][1024]
    bf16* WTk  = ws + 1 * MM;
    bf16* WTtk = ws + 2 * MM;
    bf16* WTm  = ws + 3 * MM;
    bf16* WT5  = ws + 4 * MM;        // [1024][2048] = [Wv^T | Wtv^T]
    bf16* Qb   = ws + 6 * MM;
    bf16* Kb   = ws + 10 * MM;
    bf16* TKb  = ws + 14 * MM;
    bf16* VsT  = ws + 18 * MM;       // Vsum [b*1024 + h*64 + d][s]
    bf16* ctx  = ws + 22 * MM;
    bf16* maskR = (bf16*)d_out;      // 8 MB scratch in d_out; dead before out_gemm

    PrepArgs pp;
    pp.w[0] = Wq;  pp.wdst[0] = WTq;        pp.wstride[0] = 1024;
    pp.w[1] = Wk;  pp.wdst[1] = WTk;        pp.wstride[1] = 1024;
    pp.w[2] = Wv;  pp.wdst[2] = WT5;        pp.wstride[2] = 2048;
    pp.w[3] = Wtk; pp.wdst[3] = WTtk;       pp.wstride[3] = 1024;
    pp.w[4] = Wtv; pp.wdst[4] = WT5 + 1024; pp.wstride[4] = 2048;
    pp.w[5] = Wm;  pp.wdst[5] = WTm;        pp.wstride[5] = 1024;
    pp.mask = mask; pp.maskR = maskR;
    prep_kernel<<<dim3(16, 16, 10), 256, 0, stream>>>(pp);

    ProjArgs pa;
    pa.A0[0] = query;  pa.A1[0] = nullptr; pa.W[0] = WTq;  pa.bias[0] = bq;  pa.bias2[0] = nullptr;
    pa.out[0] = Qb;  pa.vst[0] = 0; pa.nk[0] = 16;
    pa.A0[1] = key;    pa.A1[1] = nullptr; pa.W[1] = WTk;  pa.bias[1] = bk;  pa.bias2[1] = nullptr;
    pa.out[1] = Kb;  pa.vst[1] = 0; pa.nk[1] = 16;
    pa.A0[2] = time_k; pa.A1[2] = nullptr; pa.W[2] = WTtk; pa.bias[2] = btk; pa.bias2[2] = nullptr;
    pa.out[2] = TKb; pa.vst[2] = 0; pa.nk[2] = 16;
    pa.A0[3] = value;  pa.A1[3] = time_v;  pa.W[3] = WT5;  pa.bias[3] = bv;  pa.bias2[3] = btv;
    pa.out[3] = VsT; pa.vst[3] = 1; pa.nk[3] = 32;
    proj_gemm<<<dim3(32, 8, 4), 256, 0, stream>>>(pa);

    attn6_kernel<<<dim3(16, 8, 4), 256, 0, stream>>>(
        Qb, Kb, TKb, VsT, maskR, ctx);
    out_gemm<<<dim3(64, 8), 256, 0, stream>>>(ctx, WTm, bm, (float*)d_out);
}

// Round 7
// 324.887 us; speedup vs baseline: 1.1499x; 1.1499x over previous
//
#include <hip/hip_runtime.h>
#include <hip/hip_bf16.h>
#include <cstdint>
#include <cstddef>

typedef __bf16 bf16;
typedef bf16 bf16x8 __attribute__((ext_vector_type(8)));
typedef bf16 bf16x4 __attribute__((ext_vector_type(4)));
typedef float f32x4 __attribute__((ext_vector_type(4)));
typedef unsigned int u32;

#define DEV static __device__ __forceinline__

DEV f32x4 mfma16(bf16x8 a, bf16x8 b, f32x4 c) {
    return __builtin_amdgcn_mfma_f32_16x16x32_bf16(a, b, c, 0, 0, 0);
}

DEV f32x4 shflx4(f32x4 v, int m) {
    f32x4 r;
    for (int i = 0; i < 4; ++i) r[i] = __shfl_xor(v[i], m, 64);
    return r;
}

DEV bf16x8 cvt8(const float* p) {
    float4 f0 = *(const float4*)p;
    float4 f1 = *(const float4*)(p + 4);
    bf16x8 v;
    v[0] = (bf16)f0.x; v[1] = (bf16)f0.y; v[2] = (bf16)f0.z; v[3] = (bf16)f0.w;
    v[4] = (bf16)f1.x; v[5] = (bf16)f1.y; v[6] = (bf16)f1.z; v[7] = (bf16)f1.w;
    return v;
}

// async global->LDS, 16B/lane; global addr per-lane, LDS base wave-uniform.
DEV void glo(const bf16* g, bf16* l) {
    __builtin_amdgcn_global_load_lds(
        (const __attribute__((address_space(1))) u32*)g,
        (__attribute__((address_space(3))) u32*)l,
        16, 0, 0);
}

// fused "wait outstanding vmem <= n, then barrier" — counted, never reorder.
#define WAITB(n) asm volatile("s_waitcnt vmcnt(" #n ")\n\ts_barrier" ::: "memory")
#define BAR()    asm volatile("s_barrier" ::: "memory")

// ---------------------------------------------------------------------------
// Prep (weights + mask only; activation cvt is FUSED into proj_gemm):
//   z<6 : weight transpose+cvt W[K][N]fp32 -> Wt[N][K]bf16 (stride-param
//         so Wv/Wtv interleave into WT5[1024][2048])
//   z 6..9 : maskprep for b = z-6 (blockIdx.y<8 active)
// grid (16, 16, 10), 256 threads.
// ---------------------------------------------------------------------------
struct PrepArgs {
    const float* w[6];
    const float* mask;
    bf16* wdst[6];  int wstride[6];
    bf16* maskR;
};

__global__ __launch_bounds__(256) void prep_kernel(PrepArgs p)
{
    const int z = blockIdx.z;
    const int t = threadIdx.x;
    if (z < 6) {
        __shared__ bf16 tile[64][72];
        const float* src = p.w[z];
        bf16* out = p.wdst[z];
        const int os = p.wstride[z];
        const int r = t >> 3, c8 = (t & 7) * 8;
        const int row0 = blockIdx.y * 64, col0 = blockIdx.x * 64;
        *(bf16x8*)&tile[r][c8]      = cvt8(&src[(size_t)(row0 + r) * 1024 + col0 + c8]);
        *(bf16x8*)&tile[r + 32][c8] = cvt8(&src[(size_t)(row0 + r + 32) * 1024 + col0 + c8]);
        __syncthreads();
        for (int half = 0; half < 2; ++half) {
            int rr = r + half * 32;
            bf16x8 v;
            for (int j = 0; j < 8; ++j) v[j] = tile[c8 + j][rr];
            *(bf16x8*)&out[(size_t)(col0 + rr) * os + row0 + c8] = v;
        }
    } else {
        // maskprep: mask[b][i][j] fp32 -> maskR[(b,it,jt)][tid][e] bf16
        if (blockIdx.y >= 8) return;
        const int jt = blockIdx.x, it = blockIdx.y, b = z - 6;
        __shared__ bf16 Mt[128 * 72];
        const int lane = t & 63, w = t >> 6;
        const int ln = lane & 15, qd = lane >> 4;
        {
            const int il = t >> 1, jh = (t & 1) * 32;
            const float* src = &p.mask[((size_t)b * 1024 + it * 128 + il) * 1024 + jt * 64 + jh];
            *(bf16x8*)&Mt[il * 72 + jh]      = cvt8(src);
            *(bf16x8*)&Mt[il * 72 + jh + 8]  = cvt8(src + 8);
            *(bf16x8*)&Mt[il * 72 + jh + 16] = cvt8(src + 16);
            *(bf16x8*)&Mt[il * 72 + jh + 24] = cvt8(src + 24);
        }
        __syncthreads();
        bf16 m[32];
        for (int si = 0; si < 2; ++si)
            for (int jc = 0; jc < 4; ++jc)
                for (int r = 0; r < 4; ++r) {
                    const int il = w * 32 + si * 16 + qd * 4 + r;
                    const int jl = jc * 16 + ln;
                    m[(si * 4 + jc) * 4 + r] = Mt[il * 72 + jl];
                }
        bf16* dst = &p.maskR[((((size_t)b * 8 + it) * 16 + jt) * 256 + t) * 32];
        for (int c = 0; c < 4; ++c)
            *(bf16x8*)&dst[c * 8] = *(const bf16x8*)&m[c * 8];
    }
}

// ---------------------------------------------------------------------------
// Projection GEMMs, 4 z-slices. A-side reads the ORIGINAL fp32 activations,
// reg-staged with DEFERRED cvt: loadA(ks+1) issues 8 raw float4 loads (no
// consume -> no vmcnt stall); the cvt + ds_write happen at the NEXT
// iteration's write phase, one full compute phase after issue. (Round-6
// failure: cvt8 inside loadA consumed loads immediately -> vmcnt(0) before
// compute; plus __launch_bounds__(256,4) capped VGPR=64 < acc's 64 -> acc
// spilled to scratch. Both fixed: plain launch_bounds, raw-f32 defer.)
// W-side stays glo (bf16 weights). K=2048 slice (z3 = [value|time_v] @
// [Wv;Wtv]) selects source on wave-uniform bk<1024.
// 128x128 tile, 4 waves x 64x64, BK=64, XOR swizzle (0 conflicts measured).
// Grid (32 my, 8 nx, 4): linear%8 = my%8 -> same-A blocks share an XCD.
// ---------------------------------------------------------------------------
struct ProjArgs {
    const float* A0[4];
    const float* A1[4];     // source for k>=1024 (z3 only)
    const bf16* W[4];
    const float* bias[4];
    const float* bias2[4];
    bf16* out[4];
    int vst[4];
    int nk[4];
};

__global__ __launch_bounds__(256) void proj_gemm(ProjArgs pa)
{
    const int z = blockIdx.z;
    const float* __restrict__ A0 = pa.A0[z];
    const float* __restrict__ A1 = pa.A1[z];
    const bf16* __restrict__ W = pa.W[z];
    const int nk = pa.nk[z];
    const int lda = nk << 6;
    const int m0 = blockIdx.x * 128, n0 = blockIdx.y * 128;
    __shared__ bf16 As[128 * 64];
    __shared__ bf16 Bs[128 * 64];
    const int t = threadIdx.x, lane = t & 63, w = t >> 6;
    const int ln = lane & 15, qd = lane >> 4;
    const int wm0 = (w >> 1) * 64, wn0 = (w & 1) * 64;
    const int sub0 = w * 4;
    const int rr = lane >> 3;
    const int cbs = (((lane & 7) ^ rr)) * 8;   // swizzled source column
    const int lx = ln & 7;                     // row&7 for fragment rows
    f32x4 acc[4][4];
    for (int i = 0; i < 4; ++i)
        for (int j = 0; j < 4; ++j)
            acc[i][j] = (f32x4){0.f, 0.f, 0.f, 0.f};

    f32x4 araw[4][2];                          // raw fp32 A staging (deferred cvt)
    auto loadA = [&](int ks) {
        const int bk = ks * 64;
        const float* src = (bk < 1024) ? A0 : A1;   // wave-uniform
        const int acol = (bk & 1023) + cbs;
        for (int i = 0; i < 4; ++i) {
            const int row = (sub0 + i) * 8 + rr;
            const float* p = &src[(size_t)(m0 + row) * 1024 + acol];
            araw[i][0] = *(const f32x4*)p;
            araw[i][1] = *(const f32x4*)(p + 4);
        }
    };

    loadA(0);
    for (int ks = 0; ks < nk; ++ks) {
        const int bk = ks * 64;
        __syncthreads();
        for (int i = 0; i < 4; ++i) {
            const int row = (sub0 + i) * 8 + rr;
            glo(&W[(size_t)(n0 + row) * lda + bk + cbs], &Bs[(sub0 + i) * 512]);
        }
        for (int i = 0; i < 4; ++i) {
            bf16x8 v;
            for (int j = 0; j < 4; ++j) {
                v[j]     = (bf16)araw[i][0][j];
                v[4 + j] = (bf16)araw[i][1][j];
            }
            *(bf16x8*)&As[(sub0 + i) * 512 + lane * 8] = v;
        }
        __syncthreads();
        if (ks + 1 < nk) loadA(ks + 1);        // raw loads; land during compute
        for (int kc = 0; kc < 2; ++kc) {
            const int sg = ((kc * 4 + qd) ^ lx) * 8;
            bf16x8 af[4], bfr[4];
            for (int mi = 0; mi < 4; ++mi)
                af[mi] = *(const bf16x8*)&As[(wm0 + mi * 16 + ln) * 64 + sg];
            for (int ni = 0; ni < 4; ++ni)
                bfr[ni] = *(const bf16x8*)&Bs[(wn0 + ni * 16 + ln) * 64 + sg];
            for (int mi = 0; mi < 4; ++mi)
                for (int ni = 0; ni < 4; ++ni)
                    acc[mi][ni] = mfma16(af[mi], bfr[ni], acc[mi][ni]);
        }
    }
    const float* bias = pa.bias[z];
    const float* bias2 = pa.bias2[z];
    bf16* out = pa.out[z];
    const int vst = pa.vst[z];
    for (int ni = 0; ni < 4; ++ni) {
        const int n = n0 + wn0 + ni * 16 + ln;
        const float bv = bias[n] + (bias2 ? bias2[n] : 0.0f);
        for (int mi = 0; mi < 4; ++mi) {
            const int mbase = m0 + wm0 + mi * 16 + qd * 4;
            f32x4 v = acc[mi][ni];
            if (vst) {
                const int b = mbase >> 10, s = mbase & 1023;
                bf16x4 pk;
                for (int r = 0; r < 4; ++r) pk[r] = (bf16)(v[r] + bv);
                *(bf16x4*)&out[((size_t)(b * 1024 + n)) * 1024 + s] = pk;
            } else {
                for (int r = 0; r < 4; ++r)
                    out[(size_t)(mbase + r) * 1024 + n] = (bf16)(v[r] + bv);
            }
        }
    }
}

// ---------------------------------------------------------------------------
// Attention: i-tile 128, j-tile 64, grid (16h,8it,4b)=512 = 2 blocks/CU
// (grid-capped, so the double buffer is occupancy-FREE: 66.5KB < 80KB).
// Per jt: BAR (all waves past reads of buf^1) -> stage jt+1 into buf^1
// (6 glo/wave) -> vmcnt(6)+BAR (buf jt resident; jt+1 in flight under
// compute) -> QK/softmax/PV on buf jt. vmcnt never drains to 0 until jt=15.
// K/QJ/V staged via glo+XOR-swizzle; V from fused Vsum GEMM ([d][s] bf16).
// mask from maskR registers (issued before BAR, covered by vmcnt(6)).
// ---------------------------------------------------------------------------
__global__ __launch_bounds__(256) void attn6_kernel(
    const bf16* __restrict__ Qb, const bf16* __restrict__ Kb, const bf16* __restrict__ TKb,
    const bf16* __restrict__ Vsum,
    const bf16* __restrict__ maskR, bf16* __restrict__ ctx)
{
    const int h = blockIdx.x, it = blockIdx.y, b = blockIdx.z;
    const int i0 = it * 128;
    __shared__ bf16 Ks[2][64 * 64];
    __shared__ bf16 QJs[2][64 * 64];
    __shared__ bf16 Vs[2][64 * 64];
    __shared__ bf16 Ps[128][68];
    const int t = threadIdx.x, lane = t & 63, w = t >> 6;
    const int ln = lane & 15, qd = lane >> 4;
    const int lx = ln & 7;
    const int rr = lane >> 3;
    const int cbs = ((lane & 7) ^ rr) * 8;
    const size_t baseQ = ((size_t)b * 1024) * 1024 + (size_t)h * 64;
    const size_t baseV = ((size_t)b * 1024 + h * 64) * 1024;

    bf16x8 qf[2][2], tkf[2][2];
    for (int si = 0; si < 2; ++si) {
        const size_t row = (size_t)(i0 + w * 32 + si * 16 + ln);
        for (int kc = 0; kc < 2; ++kc) {
            qf[si][kc]  = *(const bf16x8*)&Qb [baseQ + row * 1024 + kc * 32 + qd * 8];
            tkf[si][kc] = *(const bf16x8*)&TKb[baseQ + row * 1024 + kc * 32 + qd * 8];
        }
    }

    f32x4 O[2][4];
    f32x4 psum[2];
    for (int si = 0; si < 2; ++si) {
        psum[si] = (f32x4){0.f, 0.f, 0.f, 0.f};
        for (int dc = 0; dc < 4; ++dc) O[si][dc] = (f32x4){0.f, 0.f, 0.f, 0.f};
    }

    const float c1 = 0.045084439f;   // log2(e)/32
    const float c2 = 1.442695041f;   // log2(e)

    const size_t mtile0 = (((size_t)b * 8 + it) * 16) * 256 + t;

    // stage j-tile jt into buffer jt&1: 24 units (6 glo per wave)
    auto stage = [&](int jt) {
        const int buf = jt & 1;
        const int j0 = jt * 64;
        for (int i = 0; i < 6; ++i) {
            const int u = w * 6 + i;
            if (u < 8) {
                glo(&Kb[baseQ + (size_t)(j0 + u * 8 + rr) * 1024 + cbs], &Ks[buf][u * 512]);
            } else if (u < 16) {
                const int s = u - 8;
                glo(&Qb[baseQ + (size_t)(j0 + s * 8 + rr) * 1024 + cbs], &QJs[buf][s * 512]);
            } else {
                const int s = u - 16;
                glo(&Vsum[baseV + (size_t)(s * 8 + rr) * 1024 + j0 + cbs], &Vs[buf][s * 512]);
            }
        }
    };

    stage(0);

    for (int jt = 0; jt < 16; ++jt) {
        const int cur = jt & 1;
        bf16x8 mm[4];
        {
            const bf16* mb = &maskR[(mtile0 + (size_t)jt * 256) * 32];
            for (int c = 0; c < 4; ++c) mm[c] = *(const bf16x8*)&mb[c * 8];
        }
        BAR();                       // all waves done reading buf[cur^1]
        if (jt < 15) {
            stage(jt + 1);           // into buf[cur^1]; stays in flight
            WAITB(6);                // buf[cur] + mm resident; 6 outstanding
        } else {
            WAITB(0);
        }

        f32x4 sc[2][4];
        for (int jc = 0; jc < 4; ++jc) {
            bf16x8 kf[2], qjf[2];
            for (int kc = 0; kc < 2; ++kc) {
                const int sg = ((kc * 4 + qd) ^ lx) * 8;
                kf[kc]  = *(const bf16x8*)&Ks [cur][(jc * 16 + ln) * 64 + sg];
                qjf[kc] = *(const bf16x8*)&QJs[cur][(jc * 16 + ln) * 64 + sg];
            }
            for (int si = 0; si < 2; ++si) {
                f32x4 a = (f32x4){0.f, 0.f, 0.f, 0.f};
                a = mfma16(qf[si][0], kf[0], a);
                a = mfma16(qf[si][1], kf[1], a);
                a = mfma16(tkf[si][0], qjf[0], a);
                a = mfma16(tkf[si][1], qjf[1], a);
                sc[si][jc] = a;
            }
        }
        for (int si = 0; si < 2; ++si) {
            const int ibl = w * 32 + si * 16 + qd * 4;
            for (int jc = 0; jc < 4; ++jc) {
                const int jl = jc * 16 + ln;
                const int e = si * 4 + jc;
                for (int r = 0; r < 4; ++r) {
                    const float mval = (float)mm[e >> 1][(e & 1) * 4 + r];
                    const float p = exp2f(fmaf(sc[si][jc][r], c1, mval * c2));
                    psum[si][r] += p;
                    Ps[ibl + r][jl] = (bf16)p;
                }
            }
        }
        for (int kc = 0; kc < 2; ++kc) {
            bf16x8 pa[2], vb[4];
            for (int si = 0; si < 2; ++si) {
                bf16x4 lo = *(const bf16x4*)&Ps[w * 32 + si * 16 + ln][kc * 32 + qd * 8];
                bf16x4 hi = *(const bf16x4*)&Ps[w * 32 + si * 16 + ln][kc * 32 + qd * 8 + 4];
                for (int e = 0; e < 4; ++e) { pa[si][e] = lo[e]; pa[si][4 + e] = hi[e]; }
            }
            for (int dc = 0; dc < 4; ++dc) {
                const int vrow = dc * 16 + ln;
                const int sg = ((kc * 4 + qd) ^ lx) * 8;
                vb[dc] = *(const bf16x8*)&Vs[cur][vrow * 64 + sg];
            }
            for (int si = 0; si < 2; ++si)
                for (int dc = 0; dc < 4; ++dc)
                    O[si][dc] = mfma16(pa[si], vb[dc], O[si][dc]);
        }
    }

    for (int si = 0; si < 2; ++si) {
        for (int m = 1; m <= 8; m <<= 1) psum[si] += shflx4(psum[si], m);
        f32x4 rl;
        for (int r = 0; r < 4; ++r) rl[r] = 1.0f / psum[si][r];
        const int ibase = i0 + w * 32 + si * 16 + qd * 4;
        for (int dc = 0; dc < 4; ++dc) {
            const int d = h * 64 + dc * 16 + ln;
            f32x4 v = O[si][dc] * rl;
            for (int r = 0; r < 4; ++r)
                ctx[((size_t)b * 1024 + ibase + r) * 1024 + d] = (bf16)v[r];
        }
    }
}

// ---------------------------------------------------------------------------
// Final GEMM: out[m][n] = ctx[m][k]*WmT[n][k] + bm, fp32 out.
// 64m x 128n tile, grid (64 my, 8 nx) = 512 = 2 blocks/CU (grid-capped ->
// double buffer free: 48KB). Same counted-vmcnt pattern as attn6.
// ---------------------------------------------------------------------------
__global__ __launch_bounds__(256) void out_gemm(
    const bf16* __restrict__ A, const bf16* __restrict__ W,
    const float* __restrict__ bias, float* __restrict__ out)
{
    const int m0 = blockIdx.x * 64, n0 = blockIdx.y * 128;
    __shared__ bf16 As[2][64 * 64];
    __shared__ bf16 Bs[2][128 * 64];
    const int t = threadIdx.x, lane = t & 63, w = t >> 6;
    const int ln = lane & 15, qd = lane >> 4;
    const int wn0 = w * 32;
    const int rr = lane >> 3;
    const int cbs = ((lane & 7) ^ rr) * 8;
    const int lx = ln & 7;
    f32x4 acc[4][2];
    for (int i = 0; i < 4; ++i)
        for (int j = 0; j < 2; ++j)
            acc[i][j] = (f32x4){0.f, 0.f, 0.f, 0.f};

    auto stage = [&](int ks) {
        const int buf = ks & 1;
        const int bk = ks * 64;
        for (int i = 0; i < 6; ++i) {
            const int u = w * 6 + i;
            if (u < 8) {
                glo(&A[(size_t)(m0 + u * 8 + rr) * 1024 + bk + cbs], &As[buf][u * 512]);
            } else {
                const int sub = u - 8;
                glo(&W[(size_t)(n0 + sub * 8 + rr) * 1024 + bk + cbs], &Bs[buf][sub * 512]);
            }
        }
    };

    stage(0);

    for (int ks = 0; ks < 16; ++ks) {
        const int cur = ks & 1;
        BAR();                       // all waves done reading buf[cur^1]
        if (ks < 15) {
            stage(ks + 1);
            WAITB(6);
        } else {
            WAITB(0);
        }
        for (int kc = 0; kc < 2; ++kc) {
            const int sg = ((kc * 4 + qd) ^ lx) * 8;
            bf16x8 af[4], bfr[2];
            for (int mi = 0; mi < 4; ++mi)
                af[mi] = *(const bf16x8*)&As[cur][(mi * 16 + ln) * 64 + sg];
            for (int ni = 0; ni < 2; ++ni)
                bfr[ni] = *(const bf16x8*)&Bs[cur][(wn0 + ni * 16 + ln) * 64 + sg];
            for (int mi = 0; mi < 4; ++mi)
                for (int ni = 0; ni < 2; ++ni)
                    acc[mi][ni] = mfma16(af[mi], bfr[ni], acc[mi][ni]);
        }
    }
    for (int ni = 0; ni < 2; ++ni) {
        const int n = n0 + wn0 + ni * 16 + ln;
        const float bv = bias[n];
        for (int mi = 0; mi < 4; ++mi) {
            const int mbase = m0 + mi * 16 + qd * 4;
            f32x4 v = acc[mi][ni];
            for (int r = 0; r < 4; ++r)
                out[(size_t)(mbase + r) * 1024 + n] = v[r] + bv;
        }
    }
}

// ---------------------------------------------------------------------------
extern "C" void kernel_launch(void* const* d_in, const int* in_sizes, int n_in,
                              void* d_out, int out_size, void* d_ws, size_t ws_size,
                              hipStream_t stream)
{
    (void)in_sizes; (void)n_in; (void)out_size; (void)ws_size;
    const float* query  = (const float*)d_in[0];
    const float* key    = (const float*)d_in[1];
    const float* value  = (const float*)d_in[2];
    const float* time_k = (const float*)d_in[3];
    const float* time_v = (const float*)d_in[4];
    const float* mask   = (const float*)d_in[5];
    const float* Wq  = (const float*)d_in[6];  const float* bq  = (const float*)d_in[7];
    const float* Wk  = (const float*)d_in[8];  const float* bk  = (const float*)d_in[9];
    const float* Wv  = (const float*)d_in[10]; const float* bv  = (const float*)d_in[11];
    const float* Wtk = (const float*)d_in[12]; const float* btk = (const float*)d_in[13];
    const float* Wtv = (const float*)d_in[14]; const float* btv = (const float*)d_in[15];
    const float* Wm  = (const float*)d_in[16]; const float* bm  = (const float*)d_in[17];

    bf16* ws = (bf16*)d_ws;
    const size_t MM = (size_t)1024 * 1024;
    bf16* WTq  = ws + 0 * MM;        // [1024][1024]
    bf16* WTk  = ws + 1 * MM;
    bf16* WTtk = ws + 2 * MM;
    bf16* WTm  = ws + 3 * MM;
    bf16* WT5  = ws + 4 * MM;        // [1024][2048] = [Wv^T | Wtv^T]
    bf16* Qb   = ws + 6 * MM;
    bf16* Kb   = ws + 10 * MM;
    bf16* TKb  = ws + 14 * MM;
    bf16* VsT  = ws + 18 * MM;       // Vsum [b*1024 + h*64 + d][s]
    bf16* ctx  = ws + 22 * MM;
    bf16* maskR = (bf16*)d_out;      // 8 MB scratch in d_out; dead before out_gemm

    PrepArgs pp;
    pp.w[0] = Wq;  pp.wdst[0] = WTq;        pp.wstride[0] = 1024;
    pp.w[1] = Wk;  pp.wdst[1] = WTk;        pp.wstride[1] = 1024;
    pp.w[2] = Wv;  pp.wdst[2] = WT5;        pp.wstride[2] = 2048;
    pp.w[3] = Wtk; pp.wdst[3] = WTtk;       pp.wstride[3] = 1024;
    pp.w[4] = Wtv; pp.wdst[4] = WT5 + 1024; pp.wstride[4] = 2048;
    pp.w[5] = Wm;  pp.wdst[5] = WTm;        pp.wstride[5] = 1024;
    pp.mask = mask; pp.maskR = maskR;
    prep_kernel<<<dim3(16, 16, 10), 256, 0, stream>>>(pp);

    ProjArgs pa;
    pa.A0[0] = query;  pa.A1[0] = nullptr; pa.W[0] = WTq;  pa.bias[0] = bq;  pa.bias2[0] = nullptr;
    pa.out[0] = Qb;  pa.vst[0] = 0; pa.nk[0] = 16;
    pa.A0[1] = key;    pa.A1[1] = nullptr; pa.W[1] = WTk;  pa.bias[1] = bk;  pa.bias2[1] = nullptr;
    pa.out[1] = Kb;  pa.vst[1] = 0; pa.nk[1] = 16;
    pa.A0[2] = time_k; pa.A1[2] = nullptr; pa.W[2] = WTtk; pa.bias[2] = btk; pa.bias2[2] = nullptr;
    pa.out[2] = TKb; pa.vst[2] = 0; pa.nk[2] = 16;
    pa.A0[3] = value;  pa.A1[3] = time_v;  pa.W[3] = WT5;  pa.bias[3] = bv;  pa.bias2[3] = btv;
    pa.out[3] = VsT; pa.vst[3] = 1; pa.nk[3] = 32;
    proj_gemm<<<dim3(32, 8, 4), 256, 0, stream>>>(pa);

    attn6_kernel<<<dim3(16, 8, 4), 256, 0, stream>>>(
        Qb, Kb, TKb, VsT, maskR, ctx);
    out_gemm<<<dim3(64, 8), 256, 0, stream>>>(ctx, WTm, bm, (float*)d_out);
}